// Round 6
// baseline (371.609 us; speedup 1.0000x reference)
//
#include <hip/hip_runtime.h>
#include <stdint.h>

typedef __attribute__((ext_vector_type(8))) short bf16x8;
typedef __attribute__((ext_vector_type(4))) float f32x4;
typedef unsigned long long ull;

typedef uint4 uint4_a __attribute__((may_alias));
typedef ull ull_a __attribute__((may_alias));
typedef bf16x8 bf16x8_a __attribute__((may_alias));
typedef f32x4 f32x4_a __attribute__((may_alias));

#define LGKM0() __builtin_amdgcn_s_waitcnt(0xc07f)
#define MFMA16(a, b, c) __builtin_amdgcn_mfma_f32_16x16x32_bf16((a), (b), (c), 0, 0, 0)

__device__ __forceinline__ unsigned f2bf(float x) {
    unsigned u = __float_as_uint(x);
    return (u + 0x7fffu + ((u >> 16) & 1u)) >> 16;
}
__device__ __forceinline__ float bf2f(short s) {
    return __uint_as_float(((unsigned)(unsigned short)s) << 16);
}
__device__ __forceinline__ ull pack4(f32x4 v) {
    return (ull)f2bf(v.x) | ((ull)f2bf(v.y) << 16) | ((ull)f2bf(v.z) << 32) | ((ull)f2bf(v.w) << 48);
}

// ---------------- prepass (parallelized dot products) --------------------------
// wsWf: fragment-ordered bf16 weights [chunk16][frag32][lane64][8]; chunk=l*8+h*2+isW2.
//   W1 chunk: frag=kk*8+gt -> W_heads[l][h][16gt+c][32kk+8q+j]
//   W2 chunk: frag=kk*8+ot -> out_W[l][16ot+c][128h+32kk+8q+j]
// h_task / Wsd: 8 lanes per output element, __shfl_xor tree reduce (latency fix:
// old version ran 128-MAC serial loops on 16 blocks -> ~79us; now 128+32 blocks).
__global__ void gat_prep(const float* __restrict__ te, const float* __restrict__ W_in,
                         const float* __restrict__ b_in, const float* __restrict__ W_heads,
                         const float* __restrict__ a_heads, const float* __restrict__ om_i,
                         const float* __restrict__ om_c, const int* __restrict__ adj,
                         const int* __restrict__ et, const float* __restrict__ out_W,
                         unsigned short* __restrict__ wsWf, unsigned short* __restrict__ wsWsd,
                         float* __restrict__ wsHt, float* __restrict__ wsEw,
                         float* __restrict__ eout) {
    const int gid = blockIdx.x, tid = threadIdx.x;
    if (gid < 1024) {  // 262144 fragment-ordered weight elements
        int idx = gid * 256 + tid;
        int j = idx & 7, lane = (idx >> 3) & 63, frag = (idx >> 9) & 31, chunk = idx >> 14;
        int cc = lane & 15, qq = lane >> 4, kk = frag >> 3, t = frag & 7;
        int l = chunk >> 3, h = (chunk >> 1) & 3;
        float v;
        if (chunk & 1)
            v = out_W[(l * 128 + 16 * t + cc) * 512 + 128 * h + 32 * kk + 8 * qq + j];
        else
            v = W_heads[((l * 4 + h) * 128 + 16 * t + cc) * 128 + 32 * kk + 8 * qq + j];
        wsWf[idx] = (unsigned short)f2bf(v);
    } else if (gid < 1056) {  // h_task[8][128] fp32: 8 lanes per output, 8 MACs each
        const int grp = tid >> 3, sg = tid & 7;
        const int idx = (gid - 1024) * 32 + grp;  // [0,1024)
        const int n = idx >> 7, o = idx & 127;
        const float4 t0 = *(const float4*)(te + n * 64 + 8 * sg);
        const float4 t1 = *(const float4*)(te + n * 64 + 8 * sg + 4);
        const float4 w0 = *(const float4*)(W_in + o * 64 + 8 * sg);
        const float4 w1 = *(const float4*)(W_in + o * 64 + 8 * sg + 4);
        float s = t0.x * w0.x + t0.y * w0.y + t0.z * w0.z + t0.w * w0.w +
                  t1.x * w1.x + t1.y * w1.y + t1.z * w1.z + t1.w * w1.w;
        s += __shfl_xor(s, 1);
        s += __shfl_xor(s, 2);
        s += __shfl_xor(s, 4);
        if (sg == 0) wsHt[idx] = s + b_in[o];
    } else if (gid < 1184) {  // Wsd[l][16][128]: 8 lanes per output, 16 MACs each
        const int grp = tid >> 3, sg = tid & 7;
        const int idx = (gid - 1056) * 32 + grp;  // [0,4096)
        const int l = idx >> 11, p = (idx >> 7) & 15, f = idx & 127;
        float s = 0.f;
        if (p < 8) {
            const int hh = p >> 1, ss = p & 1;
            const float* a = a_heads + (l * 4 + hh) * 256 + ss * 128;
            const float* Wb = W_heads + (l * 4 + hh) * 16384;
#pragma unroll
            for (int gg = 0; gg < 16; ++gg) {
                const int g = 16 * sg + gg;
                s += a[g] * Wb[g * 128 + f];
            }
        }
        s += __shfl_xor(s, 1);
        s += __shfl_xor(s, 2);
        s += __shfl_xor(s, 4);
        if (sg == 0) wsWsd[idx] = (unsigned short)f2bf(s);
    } else {  // ew
        if (tid < 64) {
            float v = 0.f;
            if (adj[tid]) {
                int t = et[tid];
                v = (t == 1) ? om_i[0] : ((t == 2) ? om_c[0] : 1.0f);
            }
            wsEw[tid] = v;
            eout[tid] = v;
        }
    }
}

// ---------------- fused GAT kernel: barrier-free, 4 waves/block ---------------
// (byte-identical to the round-3 PASSING version; do not touch without isolation)
__global__ __launch_bounds__(256, 2) void gat_main(
    const float* __restrict__ shared_emb, const float* __restrict__ out_b,
    const float* __restrict__ ln_s, const float* __restrict__ ln_b,
    const unsigned short* __restrict__ wsWf, const unsigned short* __restrict__ wsWsd,
    const float* __restrict__ wsHt, const float* __restrict__ wsEw, float* __restrict__ out) {
    __shared__ __align__(16) unsigned short sScr[4][5120];  // per-wave whT(128x40)/hp(32x136)/epilogue f32
    __shared__ __align__(16) float sE[4][32][8];            // per-wave ei/ej
    __shared__ __align__(16) unsigned short sAtt[4][32][8]; // per-wave att rows (bf16)

    const int tid = threadIdx.x;
    const int w = tid >> 6, lane = tid & 63, q = lane >> 4, c = lane & 15;
    const long wrow0 = (long)blockIdx.x * 128 + (long)w * 32;

    // X fragments (A-layout): row = 16*mt + c, f = 32*kk + 8*q + j
    bf16x8 xf[2][4];
#pragma unroll
    for (int mt = 0; mt < 2; ++mt) {
        const long row = wrow0 + 16 * mt + c;
        const size_t b = (size_t)(row >> 3);
        const int t = (int)(row & 7);
#pragma unroll
        for (int kk = 0; kk < 4; ++kk) {
            const int f0 = 32 * kk + 8 * q;
            const float4 s0 = *(const float4*)(shared_emb + b * 128 + f0);
            const float4 s1 = *(const float4*)(shared_emb + b * 128 + f0 + 4);
            const float4 h0 = *(const float4*)(wsHt + t * 128 + f0);
            const float4 h1 = *(const float4*)(wsHt + t * 128 + f0 + 4);
            float v[8] = {s0.x + h0.x, s0.y + h0.y, s0.z + h0.z, s0.w + h0.w,
                          s1.x + h1.x, s1.y + h1.y, s1.z + h1.z, s1.w + h1.w};
            bf16x8 r;
#pragma unroll
            for (int j = 0; j < 8; ++j) r[j] = (short)f2bf(v[j]);
            xf[mt][kk] = r;
        }
    }

    f32x4 gacc[8][2];  // goutT accumulators [ot][nt], persist across the 4 heads

    for (int chunk = 0; chunk < 16; ++chunk) {
        const int l = chunk >> 3, h = (chunk >> 1) & 3, isW2 = chunk & 1;
        const unsigned short* __restrict__ wf = wsWf + (size_t)chunk * 16384 + (size_t)lane * 8;
        if (!isW2) {
            if (h == 0) {  // layer start: zero gacc, E-GEMM for all heads
                const f32x4 z4 = {0.f, 0.f, 0.f, 0.f};
#pragma unroll
                for (int ot = 0; ot < 8; ++ot)
#pragma unroll
                    for (int nt = 0; nt < 2; ++nt) gacc[ot][nt] = z4;
                f32x4 e[2] = {z4, z4};
#pragma unroll
                for (int kk = 0; kk < 4; ++kk) {
                    bf16x8 bw = *(const bf16x8_a*)(wsWsd + ((l << 4) + c) * 128 + 32 * kk + 8 * q);
#pragma unroll
                    for (int mt = 0; mt < 2; ++mt) e[mt] = MFMA16(xf[mt][kk], bw, e[mt]);
                }
                if (c < 8) {
#pragma unroll
                    for (int mt = 0; mt < 2; ++mt)
#pragma unroll
                        for (int r = 0; r < 4; ++r) sE[w][16 * mt + 4 * q + r][c] = e[mt][r];
                }
                LGKM0();
            }
            if (lane < 32) {  // attention coefficients for head h: one row per lane
                const int r = lane, eb = r & 24;
                const float ei = sE[w][r][2 * h];
                float lgt[8];
#pragma unroll
                for (int m = 0; m < 8; ++m) {
                    float s = ei + sE[w][eb + m][2 * h + 1];
                    s = s > 0.f ? s : 0.2f * s;               // leaky_relu 0.2
                    lgt[m] = s * wsEw[(r & 7) * 8 + m];       // masked entries -> exactly 0
                }
                float mx = lgt[0];
#pragma unroll
                for (int m = 1; m < 8; ++m) mx = fmaxf(mx, lgt[m]);
                float p[8], sum = 0.f;
#pragma unroll
                for (int m = 0; m < 8; ++m) {
                    p[m] = __expf(lgt[m] - mx);
                    sum += p[m];
                }
                const float inv = 1.0f / sum;
                uint4 av;
                av.x = f2bf(p[0] * inv) | (f2bf(p[1] * inv) << 16);
                av.y = f2bf(p[2] * inv) | (f2bf(p[3] * inv) << 16);
                av.z = f2bf(p[4] * inv) | (f2bf(p[5] * inv) << 16);
                av.w = f2bf(p[6] * inv) | (f2bf(p[7] * inv) << 16);
                *(uint4_a*)&sAtt[w][r][0] = av;
            }
            LGKM0();  // sAtt visible; prior GEMM2/epilogue sScr reads drained before whT overwrite

            // GEMM1: Wh[row][g] = X . W1^T  (full pass, acc[mt*8+gt])
            f32x4 acc[16];
            {
                const f32x4 z4 = {0.f, 0.f, 0.f, 0.f};
#pragma unroll
                for (int i = 0; i < 16; ++i) acc[i] = z4;
            }
#pragma unroll
            for (int kk = 0; kk < 4; ++kk)
#pragma unroll
                for (int gt = 0; gt < 8; ++gt) {
                    bf16x8 bw = *(const bf16x8_a*)(wf + (size_t)(kk * 8 + gt) * 512);
#pragma unroll
                    for (int mt = 0; mt < 2; ++mt)
                        acc[mt * 8 + gt] = MFMA16(xf[mt][kk], bw, acc[mt * 8 + gt]);
                }
            // whT store: sScr[g][row] (bf16, pitch 40), packed b64 along rows
#pragma unroll
            for (int gt = 0; gt < 8; ++gt)
#pragma unroll
                for (int mt = 0; mt < 2; ++mt)
                    *(ull_a*)&sScr[w][(16 * gt + c) * 40 + 16 * mt + 4 * q] =
                        pack4(acc[mt * 8 + gt]);
            LGKM0();
            // mix-MFMA: hpT[cd][n] = sum_k WhT[cd][k] * attT[k][n] (block-diag att, K=32)
            bf16x8 bat[2];
#pragma unroll
            for (int nt = 0; nt < 2; ++nt) {
                const int n = 16 * nt + c;
                bf16x8 zb;
#pragma unroll
                for (int j = 0; j < 8; ++j) zb[j] = 0;
                bat[nt] = (q == 2 * nt + (c >> 3)) ? *(const bf16x8_a*)&sAtt[w][n][0] : zb;
            }
            {
                const f32x4 z4 = {0.f, 0.f, 0.f, 0.f};
#pragma unroll
                for (int i = 0; i < 16; ++i) acc[i] = z4;
            }
#pragma unroll
            for (int ct = 0; ct < 8; ++ct) {
                bf16x8 a0 = *(const bf16x8_a*)&sScr[w][(16 * ct + c) * 40 + 8 * q];
#pragma unroll
                for (int nt = 0; nt < 2; ++nt)
                    acc[ct * 2 + nt] = MFMA16(a0, bat[nt], acc[ct * 2 + nt]);
            }
            LGKM0();  // whT reads drained before hp overwrites scratch
            // elu + hp store: sScr[row][cd] (bf16, pitch 136)
#pragma unroll
            for (int ct = 0; ct < 8; ++ct)
#pragma unroll
                for (int nt = 0; nt < 2; ++nt) {
                    f32x4 v = acc[ct * 2 + nt];
#pragma unroll
                    for (int j = 0; j < 4; ++j) {
                        float x = v[j];
                        v[j] = x > 0.f ? x : (__expf(x) - 1.f);
                    }
                    *(ull_a*)&sScr[w][(16 * nt + c) * 136 + 16 * ct + 4 * q] = pack4(v);
                }
            LGKM0();  // hp complete before next chunk's GEMM2 reads
        } else {
            // GEMM2 (transposed out): goutT[o][n] += W2_h . hp^T
#pragma unroll
            for (int kk = 0; kk < 4; ++kk) {
                bf16x8 bh[2];
#pragma unroll
                for (int nt = 0; nt < 2; ++nt)
                    bh[nt] = *(const bf16x8_a*)&sScr[w][(16 * nt + c) * 136 + 32 * kk + 8 * q];
#pragma unroll
                for (int ot = 0; ot < 8; ++ot) {
                    bf16x8 aw = *(const bf16x8_a*)(wf + (size_t)(kk * 8 + ot) * 512);
#pragma unroll
                    for (int nt = 0; nt < 2; ++nt) gacc[ot][nt] = MFMA16(aw, bh[nt], gacc[ot][nt]);
                }
            }
            if (h == 3) {  // epilogue: residual + bias + layernorm, f32 restage per nt-tile
                LGKM0();
                float* sF = (float*)&sScr[w][0];  // [16][132] f32
                const float* ob = out_b + l * 128;
                const float* lsc = ln_s + l * 128;
                const float* lbi = ln_b + l * 128;
#pragma unroll
                for (int nt = 0; nt < 2; ++nt) {
#pragma unroll
                    for (int ot = 0; ot < 8; ++ot)
                        *(f32x4_a*)&sF[c * 132 + 16 * ot + 4 * q] = gacc[ot][nt];
                    LGKM0();
                    float sum = 0.f, ssq = 0.f;
#pragma unroll
                    for (int kk = 0; kk < 4; ++kk) {
                        const int f0 = 32 * kk + 8 * q;
                        f32x4 g0 = *(const f32x4_a*)&sF[c * 132 + f0];
                        f32x4 g1 = *(const f32x4_a*)&sF[c * 132 + f0 + 4];
                        bf16x8 x8 = xf[nt][kk];
#pragma unroll
                        for (int j = 0; j < 4; ++j) {
                            float x = g0[j] + bf2f(x8[j]) + ob[f0 + j];
                            sum += x;
                            ssq += x * x;
                            float x2 = g1[j] + bf2f(x8[4 + j]) + ob[f0 + 4 + j];
                            sum += x2;
                            ssq += x2 * x2;
                        }
                    }
                    sum += __shfl_xor(sum, 16);
                    sum += __shfl_xor(sum, 32);
                    ssq += __shfl_xor(ssq, 16);
                    ssq += __shfl_xor(ssq, 32);
                    const float mu = sum * (1.0f / 128.0f);
                    const float var = ssq * (1.0f / 128.0f) - mu * mu;
                    const float rs = rsqrtf(var + 1e-5f);
#pragma unroll
                    for (int kk = 0; kk < 4; ++kk) {
                        const int f0 = 32 * kk + 8 * q;
                        f32x4 g0 = *(const f32x4_a*)&sF[c * 132 + f0];
                        f32x4 g1 = *(const f32x4_a*)&sF[c * 132 + f0 + 4];
                        bf16x8 x8 = xf[nt][kk];
                        float y[8];
#pragma unroll
                        for (int j = 0; j < 4; ++j) {
                            float x = g0[j] + bf2f(x8[j]) + ob[f0 + j];
                            y[j] = (x - mu) * rs * lsc[f0 + j] + lbi[f0 + j];
                            float x2 = g1[j] + bf2f(x8[4 + j]) + ob[f0 + 4 + j];
                            y[4 + j] = (x2 - mu) * rs * lsc[f0 + 4 + j] + lbi[f0 + 4 + j];
                        }
                        if (l == 0) {
                            bf16x8 r;
#pragma unroll
                            for (int j = 0; j < 8; ++j) r[j] = (short)f2bf(y[j]);
                            xf[nt][kk] = r;
                        } else {
                            f32x4 o0 = {y[0], y[1], y[2], y[3]};
                            f32x4 o1 = {y[4], y[5], y[6], y[7]};
                            *(f32x4_a*)&sF[c * 132 + f0] = o0;
                            *(f32x4_a*)&sF[c * 132 + f0 + 4] = o1;
                        }
                    }
                    if (l == 1) {  // coalesced copy-out: 8 x 1KB contiguous wave stores
                        LGKM0();
#pragma unroll
                        for (int i = 0; i < 8; ++i) {
                            const int flat = i * 256 + lane * 4;
                            const int rr = flat >> 7, c0 = flat & 127;
                            f32x4 v = *(const f32x4_a*)&sF[rr * 132 + c0];
                            *(f32x4_a*)(out + (size_t)(wrow0 + 16 * nt + rr) * 128 + c0) = v;
                        }
                    }
                    LGKM0();  // drain cross-lane reads before sF is overwritten
                }
            }
        }
    }
}

extern "C" void kernel_launch(void* const* d_in, const int* in_sizes, int n_in, void* d_out,
                              int out_size, void* d_ws, size_t ws_size, hipStream_t stream) {
    const float* shared_emb = (const float*)d_in[0];
    const float* te = (const float*)d_in[1];
    const float* W_in = (const float*)d_in[2];
    const float* b_in = (const float*)d_in[3];
    const float* W_heads = (const float*)d_in[4];
    const float* a_heads = (const float*)d_in[5];
    const float* out_W = (const float*)d_in[6];
    const float* out_b = (const float*)d_in[7];
    const float* ln_s = (const float*)d_in[8];
    const float* ln_b = (const float*)d_in[9];
    const float* om_i = (const float*)d_in[10];
    const float* om_c = (const float*)d_in[11];
    const int* adj = (const int*)d_in[12];
    const int* et = (const int*)d_in[13];
    float* out = (float*)d_out;

    unsigned short* wsWf = (unsigned short*)d_ws;   // [16][32][64][8] bf16 = 524288 B
    unsigned short* wsWsd = wsWf + 262144;          // [2][16][128] bf16
    float* wsHt = (float*)((char*)d_ws + 532480);   // [8][128] f32
    float* wsEw = wsHt + 1024;                      // [64] f32
    // total ws need: 536,832 bytes (same as before)

    float* eout = out + (out_size - 64);  // ew output tail

    gat_prep<<<1185, 256, 0, stream>>>(te, W_in, b_in, W_heads, a_heads, om_i, om_c, adj, et,
                                       out_W, wsWf, wsWsd, wsHt, wsEw, eout);

    const int B = in_sizes[0] / 128;  // 16384
    const int grid = (B * 8) / 128;   // 1024 blocks, 128 rows (4 waves) each
    gat_main<<<grid, 256, 0, stream>>>(shared_emb, out_b, ln_s, ln_b, wsWf, wsWsd, wsHt, wsEw,
                                       out);
}

// Round 8
// 309.856 us; speedup vs baseline: 1.1993x; 1.1993x over previous
//
#include <hip/hip_runtime.h>
#include <stdint.h>

typedef __attribute__((ext_vector_type(8))) short bf16x8;
typedef __attribute__((ext_vector_type(4))) short bf16x4;
typedef __attribute__((ext_vector_type(4))) float f32x4;
typedef unsigned long long ull;

typedef uint4 uint4_a __attribute__((may_alias));
typedef ull ull_a __attribute__((may_alias));
typedef bf16x8 bf16x8_a __attribute__((may_alias));
typedef bf16x4 bf16x4_a __attribute__((may_alias));
typedef f32x4 f32x4_a __attribute__((may_alias));

#define LGKM0() __builtin_amdgcn_s_waitcnt(0xc07f)
#define SBAR0() __builtin_amdgcn_sched_barrier(0)
#define MFMA16(a, b, c) __builtin_amdgcn_mfma_f32_16x16x32_bf16((a), (b), (c), 0, 0, 0)

__device__ __forceinline__ unsigned f2bf(float x) {
    unsigned u = __float_as_uint(x);
    return (u + 0x7fffu + ((u >> 16) & 1u)) >> 16;
}
__device__ __forceinline__ float bf2f(short s) {
    return __uint_as_float(((unsigned)(unsigned short)s) << 16);
}
__device__ __forceinline__ ull pack4(f32x4 v) {
    return (ull)f2bf(v.x) | ((ull)f2bf(v.y) << 16) | ((ull)f2bf(v.z) << 32) | ((ull)f2bf(v.w) << 48);
}
__device__ __forceinline__ bf16x4 pkA(f32x4 v) {
    bf16x4 r;
    r[0] = (short)f2bf(v.x);
    r[1] = (short)f2bf(v.y);
    r[2] = (short)f2bf(v.z);
    r[3] = (short)f2bf(v.w);
    return r;
}
// K=16 bf16 MFMA. A-layout row=c,k=4q+j; B-layout k=4q+j,col=c; C col=c,row=4q+r.
// Device-pass-only builtin selection: host clang has no AMDGCN builtins (round-7
// failure was the host pass falling into an undeclared-name branch).
__device__ __forceinline__ f32x4 MFMA16K16(bf16x4 a, bf16x4 b, f32x4 c) {
#if defined(__HIP_DEVICE_COMPILE__)
#if __has_builtin(__builtin_amdgcn_mfma_f32_16x16x16bf16_1k)
    return __builtin_amdgcn_mfma_f32_16x16x16bf16_1k(a, b, c, 0, 0, 0);
#else
    return __builtin_amdgcn_mfma_f32_16x16x16_bf16(a, b, c, 0, 0, 0);
#endif
#else
    return c;  // host stub (never executed)
#endif
}

// ---------------- prepass (parallelized dot products) --------------------------
// wsWf: fragment-ordered bf16 weights [chunk16][frag32][lane64][8]; chunk=l*8+h*2+isW2.
//   W1 chunk: frag=kk*8+gt -> W_heads[l][h][16gt+c][32kk+8q+j]
//   W2 chunk: frag=kk*8+ot -> out_W[l][16ot+c][128h+32kk+8q+j]
__global__ void gat_prep(const float* __restrict__ te, const float* __restrict__ W_in,
                         const float* __restrict__ b_in, const float* __restrict__ W_heads,
                         const float* __restrict__ a_heads, const float* __restrict__ om_i,
                         const float* __restrict__ om_c, const int* __restrict__ adj,
                         const int* __restrict__ et, const float* __restrict__ out_W,
                         unsigned short* __restrict__ wsWf, unsigned short* __restrict__ wsWsd,
                         float* __restrict__ wsHt, float* __restrict__ wsEw,
                         float* __restrict__ eout) {
    const int gid = blockIdx.x, tid = threadIdx.x;
    if (gid < 1024) {  // 262144 fragment-ordered weight elements
        int idx = gid * 256 + tid;
        int j = idx & 7, lane = (idx >> 3) & 63, frag = (idx >> 9) & 31, chunk = idx >> 14;
        int cc = lane & 15, qq = lane >> 4, kk = frag >> 3, t = frag & 7;
        int l = chunk >> 3, h = (chunk >> 1) & 3;
        float v;
        if (chunk & 1)
            v = out_W[(l * 128 + 16 * t + cc) * 512 + 128 * h + 32 * kk + 8 * qq + j];
        else
            v = W_heads[((l * 4 + h) * 128 + 16 * t + cc) * 128 + 32 * kk + 8 * qq + j];
        wsWf[idx] = (unsigned short)f2bf(v);
    } else if (gid < 1056) {  // h_task[8][128] fp32: 8 lanes per output, 8 MACs each
        const int grp = tid >> 3, sg = tid & 7;
        const int idx = (gid - 1024) * 32 + grp;  // [0,1024)
        const int n = idx >> 7, o = idx & 127;
        const float4 t0 = *(const float4*)(te + n * 64 + 8 * sg);
        const float4 t1 = *(const float4*)(te + n * 64 + 8 * sg + 4);
        const float4 w0 = *(const float4*)(W_in + o * 64 + 8 * sg);
        const float4 w1 = *(const float4*)(W_in + o * 64 + 8 * sg + 4);
        float s = t0.x * w0.x + t0.y * w0.y + t0.z * w0.z + t0.w * w0.w +
                  t1.x * w1.x + t1.y * w1.y + t1.z * w1.z + t1.w * w1.w;
        s += __shfl_xor(s, 1);
        s += __shfl_xor(s, 2);
        s += __shfl_xor(s, 4);
        if (sg == 0) wsHt[idx] = s + b_in[o];
    } else if (gid < 1184) {  // Wsd[l][16][128]: 8 lanes per output, 16 MACs each
        const int grp = tid >> 3, sg = tid & 7;
        const int idx = (gid - 1056) * 32 + grp;  // [0,4096)
        const int l = idx >> 11, p = (idx >> 7) & 15, f = idx & 127;
        float s = 0.f;
        if (p < 8) {
            const int hh = p >> 1, ss = p & 1;
            const float* a = a_heads + (l * 4 + hh) * 256 + ss * 128;
            const float* Wb = W_heads + (l * 4 + hh) * 16384;
#pragma unroll
            for (int gg = 0; gg < 16; ++gg) {
                const int g = 16 * sg + gg;
                s += a[g] * Wb[g * 128 + f];
            }
        }
        s += __shfl_xor(s, 1);
        s += __shfl_xor(s, 2);
        s += __shfl_xor(s, 4);
        if (sg == 0) wsWsd[idx] = (unsigned short)f2bf(s);
    } else {  // ew
        if (tid < 64) {
            float v = 0.f;
            if (adj[tid]) {
                int t = et[tid];
                v = (t == 1) ? om_i[0] : ((t == 2) ? om_c[0] : 1.0f);
            }
            wsEw[tid] = v;
            eout[tid] = v;
        }
    }
}

// ---------------- fused GAT kernel: barrier-free, 4 waves/block ---------------
// Wave owns 32 rows (4 batches). All LDS per-wave; weights stream from L1/L2 as
// pre-swizzled fragments; zero __syncthreads. K=16 register-direct mix: GEMM1
// accumulator lane(q,c) holds Wh[16mt+4q+r][16gt+c], which IS the K=16 A-fragment
// whT[16gt+c][16mt+4q+j]; block-diag att confines output cols [16nt,16nt+16) to
// k in the same 16-range -> no whT LDS round-trip. Register cap kept at the
// PROVEN (256,2); sched_barrier(0) pins program order at every waitcnt.
__global__ __launch_bounds__(256, 2) void gat_main(
    const float* __restrict__ shared_emb, const float* __restrict__ out_b,
    const float* __restrict__ ln_s, const float* __restrict__ ln_b,
    const unsigned short* __restrict__ wsWf, const unsigned short* __restrict__ wsWsd,
    const float* __restrict__ wsHt, const float* __restrict__ wsEw, float* __restrict__ out) {
    __shared__ __align__(16) unsigned short sScr[4][4352];  // per-wave hp (bf16) / epilogue f32
    __shared__ __align__(16) float sE[4][32][8];            // per-wave ei/ej
    __shared__ __align__(16) unsigned short sAtt[4][32][8]; // per-wave att rows (bf16)

    const int tid = threadIdx.x;
    const int w = tid >> 6, lane = tid & 63, q = lane >> 4, c = lane & 15;
    const long wrow0 = (long)blockIdx.x * 128 + (long)w * 32;

    // X fragments (A-layout): row = 16*mt + c, f = 32*kk + 8*q + j
    bf16x8 xf[2][4];
#pragma unroll
    for (int mt = 0; mt < 2; ++mt) {
        const long row = wrow0 + 16 * mt + c;
        const size_t b = (size_t)(row >> 3);
        const int t = (int)(row & 7);
#pragma unroll
        for (int kk = 0; kk < 4; ++kk) {
            const int f0 = 32 * kk + 8 * q;
            const float4 s0 = *(const float4*)(shared_emb + b * 128 + f0);
            const float4 s1 = *(const float4*)(shared_emb + b * 128 + f0 + 4);
            const float4 h0 = *(const float4*)(wsHt + t * 128 + f0);
            const float4 h1 = *(const float4*)(wsHt + t * 128 + f0 + 4);
            float v[8] = {s0.x + h0.x, s0.y + h0.y, s0.z + h0.z, s0.w + h0.w,
                          s1.x + h1.x, s1.y + h1.y, s1.z + h1.z, s1.w + h1.w};
            bf16x8 r;
#pragma unroll
            for (int j = 0; j < 8; ++j) r[j] = (short)f2bf(v[j]);
            xf[mt][kk] = r;
        }
    }

    f32x4 gacc[8][2];  // goutT accumulators [ot][nt], persist across the 4 heads

    for (int chunk = 0; chunk < 16; ++chunk) {
        const int l = chunk >> 3, h = (chunk >> 1) & 3, isW2 = chunk & 1;
        const unsigned short* __restrict__ wf = wsWf + (size_t)chunk * 16384 + (size_t)lane * 8;
        if (!isW2) {
            if (h == 0) {  // layer start: zero gacc, E-GEMM for all heads
                const f32x4 z4 = {0.f, 0.f, 0.f, 0.f};
#pragma unroll
                for (int ot = 0; ot < 8; ++ot)
#pragma unroll
                    for (int nt = 0; nt < 2; ++nt) gacc[ot][nt] = z4;
                f32x4 e[2] = {z4, z4};
#pragma unroll
                for (int kk = 0; kk < 4; ++kk) {
                    bf16x8 bw = *(const bf16x8_a*)(wsWsd + ((l << 4) + c) * 128 + 32 * kk + 8 * q);
#pragma unroll
                    for (int mt = 0; mt < 2; ++mt) e[mt] = MFMA16(xf[mt][kk], bw, e[mt]);
                }
                if (c < 8) {
#pragma unroll
                    for (int mt = 0; mt < 2; ++mt)
#pragma unroll
                        for (int r = 0; r < 4; ++r) sE[w][16 * mt + 4 * q + r][c] = e[mt][r];
                }
                LGKM0();
                SBAR0();
            }
            if (lane < 32) {  // attention coefficients for head h: one row per lane
                const int r = lane, eb = r & 24;
                const float ei = sE[w][r][2 * h];
                float lgt[8];
#pragma unroll
                for (int m = 0; m < 8; ++m) {
                    float s = ei + sE[w][eb + m][2 * h + 1];
                    s = s > 0.f ? s : 0.2f * s;               // leaky_relu 0.2
                    lgt[m] = s * wsEw[(r & 7) * 8 + m];       // masked entries -> exactly 0
                }
                float mx = lgt[0];
#pragma unroll
                for (int m = 1; m < 8; ++m) mx = fmaxf(mx, lgt[m]);
                float p[8], sum = 0.f;
#pragma unroll
                for (int m = 0; m < 8; ++m) {
                    p[m] = __expf(lgt[m] - mx);
                    sum += p[m];
                }
                const float inv = 1.0f / sum;
                uint4 av;
                av.x = f2bf(p[0] * inv) | (f2bf(p[1] * inv) << 16);
                av.y = f2bf(p[2] * inv) | (f2bf(p[3] * inv) << 16);
                av.z = f2bf(p[4] * inv) | (f2bf(p[5] * inv) << 16);
                av.w = f2bf(p[6] * inv) | (f2bf(p[7] * inv) << 16);
                *(uint4_a*)&sAtt[w][r][0] = av;
            }
            LGKM0();  // sAtt visible; prior GEMM2/epilogue sScr reads drained before hp overwrite
            SBAR0();

            // GEMM1 in gt-halves + K=16 register-direct mix (no whT LDS round-trip)
            const f32x4 z4 = {0.f, 0.f, 0.f, 0.f};
#pragma unroll
            for (int half = 0; half < 2; ++half) {
                f32x4 acc[8];
#pragma unroll
                for (int i = 0; i < 8; ++i) acc[i] = z4;
#pragma unroll
                for (int kk = 0; kk < 4; ++kk)
#pragma unroll
                    for (int g2 = 0; g2 < 4; ++g2) {
                        const int gt = 4 * half + g2;
                        bf16x8 bw = *(const bf16x8_a*)(wf + (size_t)(kk * 8 + gt) * 512);
#pragma unroll
                        for (int mt = 0; mt < 2; ++mt)
                            acc[mt * 4 + g2] = MFMA16(xf[mt][kk], bw, acc[mt * 4 + g2]);
                    }
                // pack accumulators -> K=16 A fragments (pure-C, hazard-safe)
                bf16x4 pa[8];
#pragma unroll
                for (int i = 0; i < 8; ++i) pa[i] = pkA(acc[i]);
                // mix: hpT tile (gt,nt) = Wh-cols x attT; one K=16 MFMA per tile
                f32x4 hpt[8];
#pragma unroll
                for (int nt = 0; nt < 2; ++nt) {
                    bf16x4 bat = {0, 0, 0, 0};
                    if ((q >> 1) == (c >> 3))
                        bat = *(const bf16x4_a*)&sAtt[w][16 * nt + c][4 * (q & 1)];
#pragma unroll
                    for (int g2 = 0; g2 < 4; ++g2)
                        hpt[g2 * 2 + nt] = MFMA16K16(pa[nt * 4 + g2], bat, z4);
                }
                // elu + hp store: sScr[row n][col f] (bf16, pitch 136)
#pragma unroll
                for (int g2 = 0; g2 < 4; ++g2)
#pragma unroll
                    for (int nt = 0; nt < 2; ++nt) {
                        const int gt = 4 * half + g2;
                        f32x4 v = hpt[g2 * 2 + nt];
#pragma unroll
                        for (int j = 0; j < 4; ++j) {
                            float x = v[j];
                            v[j] = x > 0.f ? x : (__expf(x) - 1.f);
                        }
                        *(ull_a*)&sScr[w][(16 * nt + c) * 136 + 16 * gt + 4 * q] = pack4(v);
                    }
            }
            LGKM0();  // hp complete before next chunk's GEMM2 reads
            SBAR0();
        } else {
            // GEMM2 (transposed out): goutT[o][n] += W2_h . hp^T
#pragma unroll
            for (int kk = 0; kk < 4; ++kk) {
                bf16x8 bh[2];
#pragma unroll
                for (int nt = 0; nt < 2; ++nt)
                    bh[nt] = *(const bf16x8_a*)&sScr[w][(16 * nt + c) * 136 + 32 * kk + 8 * q];
#pragma unroll
                for (int ot = 0; ot < 8; ++ot) {
                    bf16x8 aw = *(const bf16x8_a*)(wf + (size_t)(kk * 8 + ot) * 512);
#pragma unroll
                    for (int nt = 0; nt < 2; ++nt) gacc[ot][nt] = MFMA16(aw, bh[nt], gacc[ot][nt]);
                }
            }
            if (h == 3) {  // epilogue: residual + bias + layernorm, f32 restage per nt-tile
                LGKM0();
                SBAR0();
                float* sF = (float*)&sScr[w][0];  // [16][132] f32 (8448 B <= 8704 B)
                const float* ob = out_b + l * 128;
                const float* lsc = ln_s + l * 128;
                const float* lbi = ln_b + l * 128;
#pragma unroll
                for (int nt = 0; nt < 2; ++nt) {
#pragma unroll
                    for (int ot = 0; ot < 8; ++ot)
                        *(f32x4_a*)&sF[c * 132 + 16 * ot + 4 * q] = gacc[ot][nt];
                    LGKM0();
                    SBAR0();
                    float sum = 0.f, ssq = 0.f;
#pragma unroll
                    for (int kk = 0; kk < 4; ++kk) {
                        const int f0 = 32 * kk + 8 * q;
                        f32x4 g0 = *(const f32x4_a*)&sF[c * 132 + f0];
                        f32x4 g1 = *(const f32x4_a*)&sF[c * 132 + f0 + 4];
                        bf16x8 x8 = xf[nt][kk];
#pragma unroll
                        for (int j = 0; j < 4; ++j) {
                            float x = g0[j] + bf2f(x8[j]) + ob[f0 + j];
                            sum += x;
                            ssq += x * x;
                            float x2 = g1[j] + bf2f(x8[4 + j]) + ob[f0 + 4 + j];
                            sum += x2;
                            ssq += x2 * x2;
                        }
                    }
                    sum += __shfl_xor(sum, 16);
                    sum += __shfl_xor(sum, 32);
                    ssq += __shfl_xor(ssq, 16);
                    ssq += __shfl_xor(ssq, 32);
                    const float mu = sum * (1.0f / 128.0f);
                    const float var = ssq * (1.0f / 128.0f) - mu * mu;
                    const float rs = rsqrtf(var + 1e-5f);
#pragma unroll
                    for (int kk = 0; kk < 4; ++kk) {
                        const int f0 = 32 * kk + 8 * q;
                        f32x4 g0 = *(const f32x4_a*)&sF[c * 132 + f0];
                        f32x4 g1 = *(const f32x4_a*)&sF[c * 132 + f0 + 4];
                        bf16x8 x8 = xf[nt][kk];
                        float y[8];
#pragma unroll
                        for (int j = 0; j < 4; ++j) {
                            float x = g0[j] + bf2f(x8[j]) + ob[f0 + j];
                            y[j] = (x - mu) * rs * lsc[f0 + j] + lbi[f0 + j];
                            float x2 = g1[j] + bf2f(x8[4 + j]) + ob[f0 + 4 + j];
                            y[4 + j] = (x2 - mu) * rs * lsc[f0 + 4 + j] + lbi[f0 + 4 + j];
                        }
                        if (l == 0) {
                            bf16x8 r;
#pragma unroll
                            for (int j = 0; j < 8; ++j) r[j] = (short)f2bf(y[j]);
                            xf[nt][kk] = r;
                        } else {
                            f32x4 o0 = {y[0], y[1], y[2], y[3]};
                            f32x4 o1 = {y[4], y[5], y[6], y[7]};
                            *(f32x4_a*)&sF[c * 132 + f0] = o0;
                            *(f32x4_a*)&sF[c * 132 + f0 + 4] = o1;
                        }
                    }
                    if (l == 1) {  // coalesced copy-out: 8 x 1KB contiguous wave stores
                        LGKM0();
                        SBAR0();
#pragma unroll
                        for (int i = 0; i < 8; ++i) {
                            const int flat = i * 256 + lane * 4;
                            const int rr = flat >> 7, c0 = flat & 127;
                            f32x4 v = *(const f32x4_a*)&sF[rr * 132 + c0];
                            *(f32x4_a*)(out + (size_t)(wrow0 + 16 * nt + rr) * 128 + c0) = v;
                        }
                    }
                    LGKM0();  // drain cross-lane reads before sF is overwritten
                    SBAR0();
                }
            }
        }
    }
}

extern "C" void kernel_launch(void* const* d_in, const int* in_sizes, int n_in, void* d_out,
                              int out_size, void* d_ws, size_t ws_size, hipStream_t stream) {
    const float* shared_emb = (const float*)d_in[0];
    const float* te = (const float*)d_in[1];
    const float* W_in = (const float*)d_in[2];
    const float* b_in = (const float*)d_in[3];
    const float* W_heads = (const float*)d_in[4];
    const float* a_heads = (const float*)d_in[5];
    const float* out_W = (const float*)d_in[6];
    const float* out_b = (const float*)d_in[7];
    const float* ln_s = (const float*)d_in[8];
    const float* ln_b = (const float*)d_in[9];
    const float* om_i = (const float*)d_in[10];
    const float* om_c = (const float*)d_in[11];
    const int* adj = (const int*)d_in[12];
    const int* et = (const int*)d_in[13];
    float* out = (float*)d_out;

    unsigned short* wsWf = (unsigned short*)d_ws;   // [16][32][64][8] bf16 = 524288 B
    unsigned short* wsWsd = wsWf + 262144;          // [2][16][128] bf16
    float* wsHt = (float*)((char*)d_ws + 532480);   // [8][128] f32
    float* wsEw = wsHt + 1024;                      // [64] f32
    // total ws need: 536,832 bytes (same as before)

    float* eout = out + (out_size - 64);  // ew output tail

    gat_prep<<<1185, 256, 0, stream>>>(te, W_in, b_in, W_heads, a_heads, om_i, om_c, adj, et,
                                       out_W, wsWf, wsWsd, wsHt, wsEw, eout);

    const int B = in_sizes[0] / 128;  // 16384
    const int grid = (B * 8) / 128;   // 1024 blocks, 128 rows (4 waves) each
    gat_main<<<grid, 256, 0, stream>>>(shared_emb, out_b, ln_s, ln_b, wsWf, wsWsd, wsHt, wsEw,
                                       out);
}